// Round 6
// baseline (194.391 us; speedup 1.0000x reference)
//
#include <hip/hip_runtime.h>

// VQ quantizer: z [8,8,16,64,64] f32, codebook [512,8] f32
// outputs concat: z_q_st (4194304 f32) | vq_loss (1 f32) | idx (524288 f32-valued)
//
// R6: MFMA split-bf16 distance filter + np-exact candidate rescue.
//  - approx dist a_k = e2_k - 2*z.e_k via one 16x16x32 bf16 MFMA per 16x16 tile,
//    K-slots: [ -2zh (x) eh | -2zh (x) el | -2zl (x) eh | 1*e2h, 1*e2l, 0.. ]
//  - pass1: per-point approx min (register + 16-lane shuffle reduce)
//  - pass2: identical MFMAs; codes with a_k <= min + eps(z2) appended to LDS
//  - phase C: owner lane evaluates candidates with the R5 np-exact chain
//    (absmax-0 validated) with order-independent first-min tie-break.
//  eps >= 2*(np rounding + split-bf16 error)  => candidate set provably
//  contains np's argmin => bit-exact. cnt>CMAX => full exact scan fallback.

#define NPTS      524288      // 8*16*64*64
#define KCODES    512
#define DDIM      8
#define CH_STRIDE 65536       // T*H*W
#define B_STRIDE  524288      // D*T*H*W
#define BLK       256
#define NTILES    32          // 512 codes / 16
#define CMAX      8
#define FLT_BIG   3.402823466e+38f

typedef short bf8 __attribute__((ext_vector_type(8)));   // 8 bf16 (4 VGPRs)
typedef float f4  __attribute__((ext_vector_type(4)));   // fp32 accum

__device__ __forceinline__ unsigned short f2bf(float f) {   // RNE f32->bf16
    unsigned u = __float_as_uint(f);
    unsigned r = u + 0x7fffu + ((u >> 16) & 1u);
    return (unsigned short)(r >> 16);
}
__device__ __forceinline__ float bf2f(unsigned short h) {
    return __uint_as_float(((unsigned)h) << 16);
}

// numpy pairwise-sum tree for n=8 (validated absmax 0, R1-R5)
__device__ __forceinline__ float np_sumsq8(const float* x) {
    float p0 = __fmul_rn(x[0], x[0]);
    float p1 = __fmul_rn(x[1], x[1]);
    float p2 = __fmul_rn(x[2], x[2]);
    float p3 = __fmul_rn(x[3], x[3]);
    float p4 = __fmul_rn(x[4], x[4]);
    float p5 = __fmul_rn(x[5], x[5]);
    float p6 = __fmul_rn(x[6], x[6]);
    float p7 = __fmul_rn(x[7], x[7]);
    return __fadd_rn(__fadd_rn(__fadd_rn(p0, p1), __fadd_rn(p2, p3)),
                     __fadd_rn(__fadd_rn(p4, p5), __fadd_rn(p6, p7)));
}

// np-exact distance (identical rounding chain to R5: absmax 0)
__device__ __forceinline__ float np_dist(const float* __restrict__ cb,
                                         const float* __restrict__ e2f,
                                         int k, const float* zv, float z2) {
    const float* c = cb + (size_t)k * DDIM;
    float ze = 0.0f;
    #pragma unroll
    for (int j = 0; j < DDIM; ++j) ze = __fmaf_rn(zv[j], c[j], ze);
    return __fmaf_rn(-2.0f, ze, __fadd_rn(z2, e2f[k]));
}

// prep: e2f[512] np-exact table + B fragments wsB[t=0..31][lane=0..63] (short8)
// B[k][n]: n=lane&15, k=(lane>>4)*8+j.  quad0: eh, quad1: el, quad2: eh,
// quad3: {e2h, e2l, 0x6}.  Thread layout: 8 blocks x 256 = 2048 = 32 tiles x 64.
__global__ void prep(const float* __restrict__ cb, float* __restrict__ e2f,
                     unsigned short* __restrict__ wsB, float* __restrict__ out_loss) {
    const int tid = blockIdx.x * 256 + threadIdx.x;
    if (tid == 0) *out_loss = 0.0f;
    const int t    = tid >> 6;
    const int lane = tid & 63;
    const int quad = lane >> 4;
    const int colc = lane & 15;
    const int n    = t * 16 + colc;
    float row[DDIM];
    #pragma unroll
    for (int j = 0; j < DDIM; ++j) row[j] = cb[n * DDIM + j];
    const float e2 = np_sumsq8(row);
    if (quad == 3) e2f[n] = e2;

    unsigned short sh[8];
    #pragma unroll
    for (int j = 0; j < 8; ++j) {
        const unsigned short eh = f2bf(row[j]);
        const unsigned short el = f2bf(__fsub_rn(row[j], bf2f(eh)));
        sh[j] = (quad == 1) ? el : eh;           // quad0/2: eh, quad1: el
    }
    if (quad == 3) {
        const unsigned short e2h = f2bf(e2);
        const unsigned short e2l = f2bf(__fsub_rn(e2, bf2f(e2h)));
        sh[0] = e2h; sh[1] = e2l;
        #pragma unroll
        for (int j = 2; j < 8; ++j) sh[j] = 0;
    }
    unsigned short* dst = wsB + (size_t)(t * 64 + lane) * 8;
    #pragma unroll
    for (int j = 0; j < 8; ++j) dst[j] = sh[j];
}

__global__ __launch_bounds__(BLK, 6) void vq_main(
    const float* __restrict__ z, const float* __restrict__ cb,
    const float* __restrict__ e2f, const unsigned short* __restrict__ wsB,
    float* __restrict__ out_zq, float* __restrict__ out_loss,
    float* __restrict__ out_idx)
{
    __shared__ int   ccnt[64];
    __shared__ int   clist[64][CMAX];
    __shared__ float wsum[4];

    const int wave = threadIdx.x >> 6;
    const int lane = threadIdx.x & 63;
    const int quad = lane >> 4;
    const int col  = lane & 15;

    if (threadIdx.x < 64) ccnt[threadIdx.x] = 0;

    // this wave handles 16 consecutive points; lane loads point (n0+col)
    const int n0 = (blockIdx.x * 4 + wave) * 16;
    const int n  = n0 + col;
    const int b  = n >> 16;
    const int s  = n & 65535;
    const float* zp = z + (size_t)b * B_STRIDE + s;

    float zv[DDIM];
    #pragma unroll
    for (int j = 0; j < DDIM; ++j) zv[j] = zp[(size_t)j * CH_STRIDE];
    const float z2 = np_sumsq8(zv);

    // A fragment: A[m=lane&15][k=quad*8+j]; quad0/1: -2*zh, quad2: -2*zl,
    // quad3: {1,1,0..} (multiplies B's {e2h,e2l,0..})
    bf8 afrag;
    #pragma unroll
    for (int j = 0; j < 8; ++j) {
        const float zh_f = bf2f(f2bf(zv[j]));
        const float v = (quad == 2) ? __fsub_rn(zv[j], zh_f) : zh_f;  // zl exact
        afrag[j] = (short)f2bf(-2.0f * v);
    }
    if (quad == 3)
        afrag = (bf8){(short)0x3F80, (short)0x3F80, 0, 0, 0, 0, 0, 0};

    const bf8* Bp = (const bf8*)wsB;

    // ---- pass 1: approx min per point ----
    float m0 = FLT_BIG, m1 = FLT_BIG, m2 = FLT_BIG, m3 = FLT_BIG;
    #pragma unroll 4
    for (int t = 0; t < NTILES; ++t) {
        const bf8 bfrag = Bp[t * 64 + lane];
        f4 acc = (f4){0.0f, 0.0f, 0.0f, 0.0f};
        acc = __builtin_amdgcn_mfma_f32_16x16x32_bf16(afrag, bfrag, acc, 0, 0, 0);
        m0 = fminf(m0, acc[0]); m1 = fminf(m1, acc[1]);
        m2 = fminf(m2, acc[2]); m3 = fminf(m3, acc[3]);
    }
    // cross-lane min over the 16 cols (lanes within quad); and wave z2 max
    float zmax = z2;
    #pragma unroll
    for (int mk = 1; mk <= 8; mk <<= 1) {
        m0 = fminf(m0, __shfl_xor(m0, mk, 64));
        m1 = fminf(m1, __shfl_xor(m1, mk, 64));
        m2 = fminf(m2, __shfl_xor(m2, mk, 64));
        m3 = fminf(m3, __shfl_xor(m3, mk, 64));
        zmax = fmaxf(zmax, __shfl_xor(zmax, mk, 64));
    }
    // eps >= 2*(np z2-rounding + final-sub rounding + fma-chain + split-bf16 err)
    const float eps  = zmax * 6e-7f + 3e-6f;
    const float thr0 = m0 + eps, thr1 = m1 + eps, thr2 = m2 + eps, thr3 = m3 + eps;

    __syncthreads();   // ccnt init visible

    // ---- pass 2: identical accs; append candidates ----
    #pragma unroll 2
    for (int t = 0; t < NTILES; ++t) {
        const bf8 bfrag = Bp[t * 64 + lane];
        f4 acc = (f4){0.0f, 0.0f, 0.0f, 0.0f};
        acc = __builtin_amdgcn_mfma_f32_16x16x32_bf16(afrag, bfrag, acc, 0, 0, 0);
        const bool c0 = acc[0] <= thr0, c1 = acc[1] <= thr1;
        const bool c2 = acc[2] <= thr2, c3 = acc[3] <= thr3;
        if (c0 | c1 | c2 | c3) {
            const int code = t * 16 + col;
            const int plb  = wave * 16 + quad * 4;   // C row = quad*4 + reg
            if (c0) { int p = atomicAdd(&ccnt[plb + 0], 1); if (p < CMAX) clist[plb + 0][p] = code; }
            if (c1) { int p = atomicAdd(&ccnt[plb + 1], 1); if (p < CMAX) clist[plb + 1][p] = code; }
            if (c2) { int p = atomicAdd(&ccnt[plb + 2], 1); if (p < CMAX) clist[plb + 2][p] = code; }
            if (c3) { int p = atomicAdd(&ccnt[plb + 3], 1); if (p < CMAX) clist[plb + 3][p] = code; }
        }
    }
    __syncthreads();

    // ---- phase C: owner lanes (0..15) resolve np-exactly ----
    float lsum = 0.0f;
    if (lane < 16) {
        const int pl  = wave * 16 + lane;   // this lane's point == its loaded zv
        const int cnt = ccnt[pl];
        float best = FLT_BIG;
        int   bidx = 0;
        if (cnt <= CMAX) {
            for (int i = 0; i < cnt; ++i) {
                const int k = clist[pl][i];
                const float d = np_dist(cb, e2f, k, zv, z2);
                // order-independent np first-min
                if (d < best || (d == best && k < bidx)) { best = d; bidx = k; }
            }
        } else {  // overflow fallback: full exact scan (correctness net)
            for (int k = 0; k < KCODES; ++k) {
                const float d = np_dist(cb, e2f, k, zv, z2);
                if (d < best) { best = d; bidx = k; }
            }
        }
        out_idx[n] = (float)bidx;

        const float* cw = cb + (size_t)bidx * DDIM;
        float* op = out_zq + (size_t)b * B_STRIDE + s;
        #pragma unroll
        for (int j = 0; j < DDIM; ++j) {
            const float zq = cw[j];
            const float t  = __fsub_rn(zq, zv[j]);            // np: z_q - z
            op[(size_t)j * CH_STRIDE] = __fadd_rn(zv[j], t);  // np: z + (z_q - z)
            lsum = __fmaf_rn(t, t, lsum);                     // loss (2% tol)
        }
    }

    // loss: reduce owner partials (lanes 16.. hold 0) -> wave -> block -> atomic
    lsum += __shfl_down(lsum, 8, 64);
    lsum += __shfl_down(lsum, 4, 64);
    lsum += __shfl_down(lsum, 2, 64);
    lsum += __shfl_down(lsum, 1, 64);
    if (lane == 0) wsum[wave] = lsum;
    __syncthreads();
    if (threadIdx.x == 0) {
        const float bs = (wsum[0] + wsum[1]) + (wsum[2] + wsum[3]);
        // vq_loss = codebk + BETA*commit = 1.25 * mean((z_q - z)^2)
        atomicAdd(out_loss, bs * (1.25f / 4194304.0f));
    }
}

extern "C" void kernel_launch(void* const* d_in, const int* in_sizes, int n_in,
                              void* d_out, int out_size, void* d_ws, size_t ws_size,
                              hipStream_t stream) {
    const float* z  = (const float*)d_in[0];
    const float* cb = (const float*)d_in[1];
    float* out      = (float*)d_out;
    float* out_zq   = out;                    // 4194304 elems
    float* out_loss = out + 4194304;          // 1 elem
    float* out_idx  = out + 4194305;          // 524288 elems (as float values)
    float* e2f            = (float*)d_ws;                 // 512 f32
    unsigned short* wsB   = (unsigned short*)((char*)d_ws + 2048);  // 32KB frags

    prep<<<8, 256, 0, stream>>>(cb, e2f, wsB, out_loss);
    vq_main<<<NPTS / 64, BLK, 0, stream>>>(z, cb, e2f, wsB,
                                           out_zq, out_loss, out_idx);
}

// Round 7
// 136.755 us; speedup vs baseline: 1.4215x; 1.4215x over previous
//
#include <hip/hip_runtime.h>

// VQ quantizer: z [8,8,16,64,64] f32, codebook [512,8] f32
// outputs concat: z_q_st (4194304 f32) | vq_loss (1 f32) | idx (524288 f32-valued)
//
// R7: R6's validated MFMA split-bf16 filter + np-exact rescue (absmax 0),
// restructured for latency: 64 points/wave (4 afrags via __shfl), B fragments
// staged once per block in LDS, every lane owns exactly one point (coalesced
// loads/stores, full-lane epilogue). Arithmetic identical to R6.

#define NPTS      524288      // 8*16*64*64
#define KCODES    512
#define DDIM      8
#define CH_STRIDE 65536       // T*H*W
#define B_STRIDE  524288      // D*T*H*W
#define BLK       256
#define NTILES    32          // 512 codes / 16
#define CMAX      8
#define FLT_BIG   3.402823466e+38f

typedef short bf8 __attribute__((ext_vector_type(8)));   // 8 bf16 (4 VGPRs)
typedef float f4  __attribute__((ext_vector_type(4)));   // fp32 accum

__device__ __forceinline__ unsigned short f2bf(float f) {   // RNE f32->bf16
    unsigned u = __float_as_uint(f);
    unsigned r = u + 0x7fffu + ((u >> 16) & 1u);
    return (unsigned short)(r >> 16);
}
__device__ __forceinline__ float bf2f(unsigned short h) {
    return __uint_as_float(((unsigned)h) << 16);
}

// numpy pairwise-sum tree for n=8 (validated absmax 0, R1-R6)
__device__ __forceinline__ float np_sumsq8(const float* x) {
    float p0 = __fmul_rn(x[0], x[0]);
    float p1 = __fmul_rn(x[1], x[1]);
    float p2 = __fmul_rn(x[2], x[2]);
    float p3 = __fmul_rn(x[3], x[3]);
    float p4 = __fmul_rn(x[4], x[4]);
    float p5 = __fmul_rn(x[5], x[5]);
    float p6 = __fmul_rn(x[6], x[6]);
    float p7 = __fmul_rn(x[7], x[7]);
    return __fadd_rn(__fadd_rn(__fadd_rn(p0, p1), __fadd_rn(p2, p3)),
                     __fadd_rn(__fadd_rn(p4, p5), __fadd_rn(p6, p7)));
}

// np-exact distance (identical rounding chain, absmax-0 validated)
__device__ __forceinline__ float np_dist(const float* __restrict__ cb,
                                         const float* __restrict__ e2f,
                                         int k, const float* zv, float z2) {
    const float* c = cb + (size_t)k * DDIM;
    float ze = 0.0f;
    #pragma unroll
    for (int j = 0; j < DDIM; ++j) ze = __fmaf_rn(zv[j], c[j], ze);
    return __fmaf_rn(-2.0f, ze, __fadd_rn(z2, e2f[k]));
}

// prep (unchanged from R6, validated): e2f table + B fragments
// B[k][n]: n=lane&15 (code), k=(lane>>4)*8+j. quad0: eh, quad1: el, quad2: eh,
// quad3: {e2h, e2l, 0x6}.
__global__ void prep(const float* __restrict__ cb, float* __restrict__ e2f,
                     unsigned short* __restrict__ wsB, float* __restrict__ out_loss) {
    const int tid = blockIdx.x * 256 + threadIdx.x;
    if (tid == 0) *out_loss = 0.0f;
    const int t    = tid >> 6;
    const int lane = tid & 63;
    const int quad = lane >> 4;
    const int colc = lane & 15;
    const int n    = t * 16 + colc;
    float row[DDIM];
    #pragma unroll
    for (int j = 0; j < DDIM; ++j) row[j] = cb[n * DDIM + j];
    const float e2 = np_sumsq8(row);
    if (quad == 3) e2f[n] = e2;

    unsigned short sh[8];
    #pragma unroll
    for (int j = 0; j < 8; ++j) {
        const unsigned short eh = f2bf(row[j]);
        const unsigned short el = f2bf(__fsub_rn(row[j], bf2f(eh)));
        sh[j] = (quad == 1) ? el : eh;
    }
    if (quad == 3) {
        const unsigned short e2h = f2bf(e2);
        const unsigned short e2l = f2bf(__fsub_rn(e2, bf2f(e2h)));
        sh[0] = e2h; sh[1] = e2l;
        #pragma unroll
        for (int j = 2; j < 8; ++j) sh[j] = 0;
    }
    unsigned short* dst = wsB + (size_t)(t * 64 + lane) * 8;
    #pragma unroll
    for (int j = 0; j < 8; ++j) dst[j] = sh[j];
}

__global__ __launch_bounds__(BLK, 3) void vq_main(
    const float* __restrict__ z, const float* __restrict__ cb,
    const float* __restrict__ e2f, const unsigned short* __restrict__ wsB,
    float* __restrict__ out_zq, float* __restrict__ out_loss,
    float* __restrict__ out_idx)
{
    __shared__ unsigned short ldsB[NTILES * 64 * 8];   // 32 KB
    __shared__ int   ccnt[BLK];                        // 1 KB
    __shared__ int   clist[BLK][CMAX];                 // 8 KB
    __shared__ float wsum[4];

    const int tid  = threadIdx.x;
    const int wave = tid >> 6;
    const int lane = tid & 63;
    const int quad = lane >> 4;
    const int col  = lane & 15;

    // stage B fragments global -> LDS (32 KB, coalesced uint4)
    {
        const uint4* src = (const uint4*)wsB;
        uint4* dst = (uint4*)ldsB;
        #pragma unroll
        for (int q = 0; q < 8; ++q)
            dst[tid + q * BLK] = src[tid + q * BLK];
    }
    ccnt[tid] = 0;

    // lane owns point n (1 point/thread): fully coalesced loads
    const int n = blockIdx.x * BLK + tid;
    const int b = n >> 16;
    const int s = n & 65535;
    const float* zp = z + (size_t)b * B_STRIDE + s;
    float zv[DDIM];
    #pragma unroll
    for (int j = 0; j < DDIM; ++j) zv[j] = zp[(size_t)j * CH_STRIDE];
    const float z2 = np_sumsq8(zv);

    // wave-wide z2 max -> eps (>= per-point bound; R6 constants, validated)
    float zmax = z2;
    #pragma unroll
    for (int mk = 1; mk <= 32; mk <<= 1) zmax = fmaxf(zmax, __shfl_xor(zmax, mk, 64));
    const float eps = zmax * 6e-7f + 3e-6f;

    // Build 4 afrags: ptile q covers this wave's points q*16..q*16+15 (lane-owned).
    // afrag_q at lane (col,quad): A[m=col][k=quad*8+j] from owner lane q*16+col.
    // quad0/1: -2*zh, quad2: -2*zl, quad3: {1,1,0..}  (R6 content, validated)
    bf8 af0, af1, af2, af3;
#define MK_AFRAG(AF, Q)                                                        \
    {                                                                          \
        const int srcl = (Q)*16 + col;                                         \
        _Pragma("unroll")                                                      \
        for (int j = 0; j < 8; ++j) {                                          \
            const float raw = __shfl(zv[j], srcl, 64);                         \
            const unsigned short h = f2bf(raw);                                \
            const float zh = bf2f(h);                                          \
            const float v = (quad == 2) ? __fsub_rn(raw, zh) : zh;             \
            AF[j] = (short)f2bf(-2.0f * v);                                    \
        }                                                                      \
        if (quad == 3) AF = (bf8){(short)0x3F80, (short)0x3F80, 0, 0, 0, 0, 0, 0}; \
    }
    MK_AFRAG(af0, 0) MK_AFRAG(af1, 1) MK_AFRAG(af2, 2) MK_AFRAG(af3, 3)

    __syncthreads();   // ldsB + ccnt visible

    const bf8* Bp = (const bf8*)ldsB;

    // ---- pass 1: approx min per point (4 ptiles x 4 regs held in f4) ----
    f4 mn0 = (f4){FLT_BIG, FLT_BIG, FLT_BIG, FLT_BIG};
    f4 mn1 = mn0, mn2 = mn0, mn3 = mn0;
    #pragma unroll 4
    for (int t = 0; t < NTILES; ++t) {
        const bf8 bfrag = Bp[t * 64 + lane];
        f4 zero = (f4){0.0f, 0.0f, 0.0f, 0.0f};
        const f4 a0 = __builtin_amdgcn_mfma_f32_16x16x32_bf16(af0, bfrag, zero, 0, 0, 0);
        const f4 a1 = __builtin_amdgcn_mfma_f32_16x16x32_bf16(af1, bfrag, zero, 0, 0, 0);
        const f4 a2 = __builtin_amdgcn_mfma_f32_16x16x32_bf16(af2, bfrag, zero, 0, 0, 0);
        const f4 a3 = __builtin_amdgcn_mfma_f32_16x16x32_bf16(af3, bfrag, zero, 0, 0, 0);
        #pragma unroll
        for (int r = 0; r < 4; ++r) {
            mn0[r] = fminf(mn0[r], a0[r]); mn1[r] = fminf(mn1[r], a1[r]);
            mn2[r] = fminf(mn2[r], a2[r]); mn3[r] = fminf(mn3[r], a3[r]);
        }
    }
    // min across the 16 cols (xor bits 0..3), then add eps -> thresholds
    #pragma unroll
    for (int mk = 1; mk <= 8; mk <<= 1) {
        #pragma unroll
        for (int r = 0; r < 4; ++r) {
            mn0[r] = fminf(mn0[r], __shfl_xor(mn0[r], mk, 64));
            mn1[r] = fminf(mn1[r], __shfl_xor(mn1[r], mk, 64));
            mn2[r] = fminf(mn2[r], __shfl_xor(mn2[r], mk, 64));
            mn3[r] = fminf(mn3[r], __shfl_xor(mn3[r], mk, 64));
        }
    }
    #pragma unroll
    for (int r = 0; r < 4; ++r) {
        mn0[r] += eps; mn1[r] += eps; mn2[r] += eps; mn3[r] += eps;
    }

    // ---- pass 2: identical accs; append candidates to per-point LDS lists ----
    // C layout: point = wave*64 + q*16 + quad*4 + r, code = t*16 + col (validated R6)
    #pragma unroll 2
    for (int t = 0; t < NTILES; ++t) {
        const bf8 bfrag = Bp[t * 64 + lane];
        f4 zero = (f4){0.0f, 0.0f, 0.0f, 0.0f};
        const f4 a0 = __builtin_amdgcn_mfma_f32_16x16x32_bf16(af0, bfrag, zero, 0, 0, 0);
        const f4 a1 = __builtin_amdgcn_mfma_f32_16x16x32_bf16(af1, bfrag, zero, 0, 0, 0);
        const f4 a2 = __builtin_amdgcn_mfma_f32_16x16x32_bf16(af2, bfrag, zero, 0, 0, 0);
        const f4 a3 = __builtin_amdgcn_mfma_f32_16x16x32_bf16(af3, bfrag, zero, 0, 0, 0);
        const int code = t * 16 + col;
        const int pb   = wave * 64 + quad * 4;
#define PUSH(AQ, MQ, Q)                                                        \
    {                                                                          \
        const bool c0 = AQ[0] <= MQ[0], c1 = AQ[1] <= MQ[1];                   \
        const bool c2 = AQ[2] <= MQ[2], c3 = AQ[3] <= MQ[3];                   \
        if (c0 | c1 | c2 | c3) {                                               \
            const int pt = pb + (Q)*16;                                        \
            if (c0) { int p = atomicAdd(&ccnt[pt + 0], 1); if (p < CMAX) clist[pt + 0][p] = code; } \
            if (c1) { int p = atomicAdd(&ccnt[pt + 1], 1); if (p < CMAX) clist[pt + 1][p] = code; } \
            if (c2) { int p = atomicAdd(&ccnt[pt + 2], 1); if (p < CMAX) clist[pt + 2][p] = code; } \
            if (c3) { int p = atomicAdd(&ccnt[pt + 3], 1); if (p < CMAX) clist[pt + 3][p] = code; } \
        }                                                                      \
    }
        PUSH(a0, mn0, 0) PUSH(a1, mn1, 1) PUSH(a2, mn2, 2) PUSH(a3, mn3, 3)
    }
    __syncthreads();

    // ---- phase C: every lane resolves its own point np-exactly ----
    const int cnt = ccnt[tid];
    float best = FLT_BIG;
    int   bidx = 0;
    if (cnt <= CMAX) {
        for (int i = 0; i < cnt; ++i) {
            const int k = clist[tid][i];
            const float d = np_dist(cb, e2f, k, zv, z2);
            // order-independent np first-min
            if (d < best || (d == best && k < bidx)) { best = d; bidx = k; }
        }
    } else {  // overflow fallback: full exact scan (correctness net)
        for (int k = 0; k < KCODES; ++k) {
            const float d = np_dist(cb, e2f, k, zv, z2);
            if (d < best) { best = d; bidx = k; }
        }
    }
    out_idx[n] = (float)bidx;

    const float* cw = cb + (size_t)bidx * DDIM;
    float* op = out_zq + (size_t)b * B_STRIDE + s;
    float lsum = 0.0f;
    #pragma unroll
    for (int j = 0; j < DDIM; ++j) {
        const float zq = cw[j];
        const float t  = __fsub_rn(zq, zv[j]);            // np: z_q - z
        op[(size_t)j * CH_STRIDE] = __fadd_rn(zv[j], t);  // np: z + (z_q - z)
        lsum = __fmaf_rn(t, t, lsum);                     // loss (2% tol)
    }

    // loss: wave butterfly -> LDS -> one atomic/block
    #pragma unroll
    for (int off = 32; off > 0; off >>= 1) lsum += __shfl_down(lsum, off, 64);
    if (lane == 0) wsum[wave] = lsum;
    __syncthreads();
    if (tid == 0) {
        const float bs = (wsum[0] + wsum[1]) + (wsum[2] + wsum[3]);
        // vq_loss = codebk + BETA*commit = 1.25 * mean((z_q - z)^2)
        atomicAdd(out_loss, bs * (1.25f / 4194304.0f));
    }
}

extern "C" void kernel_launch(void* const* d_in, const int* in_sizes, int n_in,
                              void* d_out, int out_size, void* d_ws, size_t ws_size,
                              hipStream_t stream) {
    const float* z  = (const float*)d_in[0];
    const float* cb = (const float*)d_in[1];
    float* out      = (float*)d_out;
    float* out_zq   = out;                    // 4194304 elems
    float* out_loss = out + 4194304;          // 1 elem
    float* out_idx  = out + 4194305;          // 524288 elems (as float values)
    float* e2f            = (float*)d_ws;                           // 512 f32
    unsigned short* wsB   = (unsigned short*)((char*)d_ws + 2048);  // 32KB frags

    prep<<<8, 256, 0, stream>>>(cb, e2f, wsB, out_loss);
    vq_main<<<NPTS / BLK, BLK, 0, stream>>>(z, cb, e2f, wsB,
                                            out_zq, out_loss, out_idx);
}